// Round 17
// baseline (1671.491 us; speedup 1.0000x reference)
//
#include <hip/hip_runtime.h>
#include <hip/hip_bf16.h>
#include <hip/hip_cooperative_groups.h>
#include <math.h>

namespace cg = cooperative_groups;

#define BB 2
#define LL 1024
#define DIM 512
#define NL 6
#define DI 1024
#define DS 16
#define DC 4
#define DR 32
#define VOCAB 32000
#define M_ROWS (BB * LL)   // 2048
#define CCH 64             // scan chunks
#define CHLEN (LL / CCH)   // 16
#define KSPLIT 8           // x_proj K-split
#define OSPLIT 2           // out_proj K-split

typedef unsigned short u16;
typedef __attribute__((ext_vector_type(8))) short bf16x8;
typedef __attribute__((ext_vector_type(4))) float f32x4;

__device__ __forceinline__ u16 f2bf(float f) {
    unsigned u = __float_as_uint(f);
    u += 0x7FFF + ((u >> 16) & 1);       // round-to-nearest-even
    return (u16)(u >> 16);
}
__device__ __forceinline__ float bf2f(u16 h) {
    return __uint_as_float(((unsigned)h) << 16);
}
// LDS chunk swizzle: row r, 16B-chunk c -> c ^ ((r>>1)&3)  (involution)
#define SWZ(r, c) ((c) ^ (((r) >> 1) & 3))

// ---------------------------------------------------------------------------
// fused fp32 -> bf16 weight cast (lm_w, in_w, ow, xpw)
// ---------------------------------------------------------------------------
__global__ __launch_bounds__(256) void cast_all(const float* __restrict__ lm,
                                                const float* __restrict__ inw,
                                                const float* __restrict__ ow,
                                                const float* __restrict__ xp,
                                                u16* __restrict__ lmb,
                                                u16* __restrict__ inb,
                                                u16* __restrict__ owb_,
                                                u16* __restrict__ xpb) {
    int idx = blockIdx.x * 256 + threadIdx.x;
    const float* src; u16* dst; int off;
    if (idx < 2048000)      { src = lm;  dst = lmb;  off = idx; }
    else if (idx < 2834432) { src = inw; dst = inb;  off = idx - 2048000; }
    else if (idx < 3227648) { src = ow;  dst = owb_; off = idx - 2834432; }
    else                    { src = xp;  dst = xpb;  off = idx - 3227648; }
    float4 v0 = ((const float4*)src)[off * 2];
    float4 v1 = ((const float4*)src)[off * 2 + 1];
    union { u16 h[8]; int4 v; } r;
    r.h[0] = f2bf(v0.x); r.h[1] = f2bf(v0.y); r.h[2] = f2bf(v0.z); r.h[3] = f2bf(v0.w);
    r.h[4] = f2bf(v1.x); r.h[5] = f2bf(v1.y); r.h[6] = f2bf(v1.z); r.h[7] = f2bf(v1.w);
    ((int4*)dst)[off] = r.v;
}

// ---------------------------------------------------------------------------
// embed + pos  (f32 x + bf16 shadow xb)
// ---------------------------------------------------------------------------
__global__ __launch_bounds__(256) void embed_kernel(const int* __restrict__ tok,
                                                    const float* __restrict__ pos,
                                                    const float* __restrict__ emb,
                                                    float* __restrict__ x,
                                                    u16* __restrict__ xb) {
    int idx = blockIdx.x * 256 + threadIdx.x;
    int d = idx & (DIM - 1);
    int l = (idx >> 9) & (LL - 1);
    int b = idx >> 19;
    int t = tok[b * LL + l];
    float v = emb[(size_t)t * DIM + d] + pos[l * DIM + d];
    x[idx] = v;
    xb[idx] = f2bf(v);
}

// ---------------------------------------------------------------------------
// 256x256 bf16 MFMA GEMM (LM head): 512 thr / 8 waves (2M x 4N),
// per-wave 128x64 (acc[8][4]).  BK=32, 3-buffer dist-2 counted vmcnt(8).
// LDS 96 KB staging (reused as 64x260 f32 C-stage); setprio on MFMA.
// ---------------------------------------------------------------------------
__global__ __launch_bounds__(512) void gemm_256(const u16* __restrict__ A,
                                                const u16* __restrict__ W,
                                                float* __restrict__ C,
                                                const float* __restrict__ bias,
                                                int K, int N) {
    __shared__ __align__(16) char smem_raw[98304];   // 3x16K A | 3x16K B ; C-stage
    u16* As = (u16*)smem_raw;                        // 3 * 8192 u16
    u16* Ws = (u16*)(smem_raw + 49152);              // 3 * 8192 u16
    float* Cs = (float*)smem_raw;                    // 64 x 260 f32

    const int t = threadIdx.x;                       // 0..511
    const int l = t & 63;
    const int w = t >> 6;                            // wave 0..7
    const int wr = w >> 2;                           // 0..1  (M dir)
    const int wc = w & 3;                            // 0..3  (N dir)

    const int nwg = gridDim.x;
    const int q8 = nwg >> 3, r8 = nwg & 7;
    const int xcd = blockIdx.x & 7, rank = blockIdx.x >> 3;
    const int wgid = (xcd < r8 ? xcd * (q8 + 1) : r8 * (q8 + 1) + (xcd - r8) * q8) + rank;
    const int bm = (wgid & 7) * 256;
    const int bn = (wgid >> 3) * 256;

    f32x4 acc[8][4] = {};
    const int nt = K >> 5;                           // 16 for K=512

    auto STAGE = [&](int bufi, int k0) {
#pragma unroll
        for (int p = 0; p < 2; ++p) {
            const int g = p * 512 + t;               // chunk id 0..1023
            const int row = g >> 2, slot = g & 3;
            __builtin_amdgcn_global_load_lds(
                (const __attribute__((address_space(1))) unsigned int*)
                    (A + (size_t)(bm + row) * K + k0 + SWZ(row, slot) * 8),
                (__attribute__((address_space(3))) unsigned int*)
                    (As + bufi * 8192 + (p * 512 + w * 64) * 8),
                16, 0, 0);
        }
#pragma unroll
        for (int p = 0; p < 2; ++p) {
            const int g = p * 512 + t;
            const int row = g >> 2, slot = g & 3;
            __builtin_amdgcn_global_load_lds(
                (const __attribute__((address_space(1))) unsigned int*)
                    (W + (size_t)(bn + row) * K + k0 + SWZ(row, slot) * 8),
                (__attribute__((address_space(3))) unsigned int*)
                    (Ws + bufi * 8192 + (p * 512 + w * 64) * 8),
                16, 0, 0);
        }
    };
    auto COMPUTE = [&](int bufi) {
        const u16* Ab = As + bufi * 8192;
        const u16* Wb = Ws + bufi * 8192;
        bf16x8 bfr[4];
#pragma unroll
        for (int ni = 0; ni < 4; ++ni) {
            const int wrow = wc * 64 + ni * 16 + (l & 15);
            bfr[ni] = *(const bf16x8*)(Wb + wrow * 32 + SWZ(wrow, l >> 4) * 8);
        }
        __builtin_amdgcn_s_setprio(1);
#pragma unroll
        for (int mi = 0; mi < 8; ++mi) {
            const int arow = wr * 128 + mi * 16 + (l & 15);
            bf16x8 a = *(const bf16x8*)(Ab + arow * 32 + SWZ(arow, l >> 4) * 8);
#pragma unroll
            for (int ni = 0; ni < 4; ++ni)
                acc[mi][ni] = __builtin_amdgcn_mfma_f32_16x16x32_bf16(bfr[ni], a, acc[mi][ni], 0, 0, 0);
        }
        __builtin_amdgcn_s_setprio(0);
    };

    STAGE(0, 0);
    STAGE(1, 32);
    int b0 = 0;
    for (int tt = 0; tt < nt - 2; ++tt) {
        int b2 = b0 + 2; if (b2 >= 3) b2 -= 3;
        STAGE(b2, (tt + 2) << 5);
        asm volatile("s_waitcnt vmcnt(8)\ns_barrier" ::: "memory");
        COMPUTE(b0);
        asm volatile("s_waitcnt lgkmcnt(0)\ns_barrier" ::: "memory");
        ++b0; if (b0 == 3) b0 = 0;
    }
    asm volatile("s_waitcnt vmcnt(4)\ns_barrier" ::: "memory");
    COMPUTE(b0);
    asm volatile("s_waitcnt lgkmcnt(0)\ns_barrier" ::: "memory");
    ++b0; if (b0 == 3) b0 = 0;
    asm volatile("s_waitcnt vmcnt(0)\ns_barrier" ::: "memory");
    COMPUTE(b0);
    asm volatile("s_waitcnt lgkmcnt(0)" ::: "memory");
    __syncthreads();

    // epilogue: 4 passes of 64 rows x 256 cols via LDS (1 KB/row stores)
#pragma unroll
    for (int pass = 0; pass < 4; ++pass) {
        if (wr == (pass >> 1)) {
            const int pm0 = (pass & 1) * 4;
#pragma unroll
            for (int mi2 = 0; mi2 < 4; ++mi2) {
                const int r = mi2 * 16 + (l & 15);
#pragma unroll
                for (int ni = 0; ni < 4; ++ni) {
                    const int c = wc * 64 + ni * 16 + ((l >> 4) << 2);
                    float4 v;
                    v.x = acc[pm0 + mi2][ni][0]; v.y = acc[pm0 + mi2][ni][1];
                    v.z = acc[pm0 + mi2][ni][2]; v.w = acc[pm0 + mi2][ni][3];
                    *(float4*)(Cs + r * 260 + c) = v;
                }
            }
        }
        __syncthreads();
#pragma unroll
        for (int it = 0; it < 8; ++it) {
            const int idx = it * 512 + t;            // 0..4095
            const int r = idx >> 6;
            const int c4 = (idx & 63) * 4;
            float4 v = *(float4*)(Cs + r * 260 + c4);
            if (bias != nullptr) {
                float4 b4 = *(const float4*)(bias + bn + c4);
                v.x += b4.x; v.y += b4.y; v.z += b4.z; v.w += b4.w;
            }
            *(float4*)(C + (size_t)(bm + pass * 64 + r) * N + bn + c4) = v;
        }
        __syncthreads();
    }
}

// ---------------------------------------------------------------------------
// bf16 MFMA GEMM, 128M x 64N tile, BK=32, K-split, 3-buffer dist-2.
// (layer GEMMs)  f32 out: LDS-staged epilogue + bias; bf16 out: direct.
// ---------------------------------------------------------------------------
__global__ __launch_bounds__(256) void gemm_n64(const u16* __restrict__ A,
                                                const u16* __restrict__ W,
                                                float* __restrict__ out,
                                                u16* __restrict__ outb,
                                                const float* __restrict__ bias,
                                                int lda, int ldw, int ldc,
                                                int KS, int pstride) {
    __shared__ __align__(16) char smem_raw[36864];   // As 24K | Ws 12K ; C-stage reuse
    u16* As = (u16*)smem_raw;
    u16* Ws = (u16*)(smem_raw + 24576);
    float* Cs = (float*)smem_raw;

    const int t = threadIdx.x;
    const int l = t & 63;
    const int w = t >> 6;
    const int gx = gridDim.x, gy = gridDim.y;
    const int nwg = gx * gy * gridDim.z;
    const int fid = (blockIdx.z * gy + blockIdx.y) * gx + blockIdx.x;
    const int q8 = nwg >> 3, r8 = nwg & 7;
    const int xcd = fid & 7, rank = fid >> 3;
    const int wgid = (xcd < r8 ? xcd * (q8 + 1) : r8 * (q8 + 1) + (xcd - r8) * q8) + rank;
    const int kz = wgid % gx;
    const int bm = ((wgid / gx) % gy) * 128;
    const int bnn = (wgid / (gx * gy)) * 64;
    const int wm = w * 32;

    f32x4 acc[2][4] = {};
    const int nt = KS >> 5;
    const int kbeg = kz * KS;

    auto STAGE = [&](int bufi, int k0) {
#pragma unroll
        for (int p = 0; p < 2; ++p) {
            const int i = p * 256 + w * 64 + l;
            const int row = i >> 2;
            const int kq = SWZ(row, i & 3);
            __builtin_amdgcn_global_load_lds(
                (const __attribute__((address_space(1))) unsigned int*)
                    (A + (size_t)(bm + row) * lda + k0 + kq * 8),
                (__attribute__((address_space(3))) unsigned int*)
                    (As + bufi * 4096 + (p * 256 + w * 64) * 8),
                16, 0, 0);
        }
        {
            const int i = w * 64 + l;
            const int row = i >> 2;
            const int kq = SWZ(row, i & 3);
            __builtin_amdgcn_global_load_lds(
                (const __attribute__((address_space(1))) unsigned int*)
                    (W + (size_t)(bnn + row) * ldw + k0 + kq * 8),
                (__attribute__((address_space(3))) unsigned int*)
                    (Ws + bufi * 2048 + (w * 64) * 8),
                16, 0, 0);
        }
    };
    auto COMPUTE = [&](int bufi) {
        const u16* Ab = As + bufi * 4096;
        const u16* Wb = Ws + bufi * 2048;
        bf16x8 bfr[4];
#pragma unroll
        for (int ni = 0; ni < 4; ++ni) {
            const int wr2 = ni * 16 + (l & 15);
            bfr[ni] = *(const bf16x8*)(Wb + wr2 * 32 + SWZ(wr2, l >> 4) * 8);
        }
        __builtin_amdgcn_s_setprio(1);
#pragma unroll
        for (int mi = 0; mi < 2; ++mi) {
            const int ar = wm + mi * 16 + (l & 15);
            bf16x8 a = *(const bf16x8*)(Ab + ar * 32 + SWZ(ar, l >> 4) * 8);
#pragma unroll
            for (int ni = 0; ni < 4; ++ni)
                acc[mi][ni] = __builtin_amdgcn_mfma_f32_16x16x32_bf16(bfr[ni], a, acc[mi][ni], 0, 0, 0);
        }
        __builtin_amdgcn_s_setprio(0);
    };

    STAGE(0, kbeg);
    if (nt == 1) {
        asm volatile("s_waitcnt vmcnt(0)\ns_barrier" ::: "memory");
        COMPUTE(0);
        asm volatile("s_waitcnt lgkmcnt(0)" ::: "memory");
    } else {
        STAGE(1, kbeg + 32);
        int b0 = 0;
        for (int tt = 0; tt < nt - 2; ++tt) {
            int b2 = b0 + 2; if (b2 >= 3) b2 -= 3;
            STAGE(b2, kbeg + ((tt + 2) << 5));
            asm volatile("s_waitcnt vmcnt(6)\ns_barrier" ::: "memory");
            COMPUTE(b0);
            asm volatile("s_waitcnt lgkmcnt(0)\ns_barrier" ::: "memory");
            ++b0; if (b0 == 3) b0 = 0;
        }
        asm volatile("s_waitcnt vmcnt(3)\ns_barrier" ::: "memory");
        COMPUTE(b0);
        asm volatile("s_waitcnt lgkmcnt(0)\ns_barrier" ::: "memory");
        ++b0; if (b0 == 3) b0 = 0;
        asm volatile("s_waitcnt vmcnt(0)\ns_barrier" ::: "memory");
        COMPUTE(b0);
        asm volatile("s_waitcnt lgkmcnt(0)" ::: "memory");
    }

    if (outb != nullptr) {
        u16* opb = outb + (size_t)kz * pstride;
#pragma unroll
        for (int mi = 0; mi < 2; ++mi) {
            const int row = bm + wm + mi * 16 + (l & 15);
#pragma unroll
            for (int ni = 0; ni < 4; ++ni) {
                const int col = bnn + ni * 16 + ((l >> 4) << 2);
                ushort4 v;
                v.x = f2bf(acc[mi][ni][0]); v.y = f2bf(acc[mi][ni][1]);
                v.z = f2bf(acc[mi][ni][2]); v.w = f2bf(acc[mi][ni][3]);
                *(ushort4*)(opb + (size_t)row * ldc + col) = v;
            }
        }
    } else {
        float* op = out + (size_t)kz * pstride;
        __syncthreads();
#pragma unroll
        for (int pass = 0; pass < 2; ++pass) {
            if ((w >> 1) == pass) {
                const int rbase = (w & 1) * 32;
#pragma unroll
                for (int mi = 0; mi < 2; ++mi) {
                    const int r = rbase + mi * 16 + (l & 15);
#pragma unroll
                    for (int ni = 0; ni < 4; ++ni) {
                        const int c = ni * 16 + ((l >> 4) << 2);
                        float4 v;
                        v.x = acc[mi][ni][0]; v.y = acc[mi][ni][1];
                        v.z = acc[mi][ni][2]; v.w = acc[mi][ni][3];
                        *(float4*)(Cs + r * 65 + c) = v;
                    }
                }
            }
            __syncthreads();
#pragma unroll
            for (int it = 0; it < 4; ++it) {
                const int idx = it * 256 + t;
                const int r = idx >> 4;
                const int c4 = (idx & 15) * 4;
                float4 v = *(float4*)(Cs + r * 65 + c4);
                if (bias != nullptr) {
                    float4 b4 = *(const float4*)(bias + bnn + c4);
                    v.x += b4.x; v.y += b4.y; v.z += b4.z; v.w += b4.w;
                }
                *(float4*)(op + (size_t)(bm + pass * 64 + r) * ldc + bnn + c4) = v;
            }
            __syncthreads();
        }
    }
}

// ---------------------------------------------------------------------------
// causal depthwise conv (DC=4) + SiLU, 8 channels/thread (short8 I/O)
// ---------------------------------------------------------------------------
__global__ __launch_bounds__(256) void conv_silu(const u16* __restrict__ xzb,
                                                 const float* __restrict__ cw,
                                                 const float* __restrict__ cb,
                                                 u16* __restrict__ xcb) {
    int idx8 = blockIdx.x * 256 + threadIdx.x;
    int c0 = (idx8 & 127) * 8;
    int m = idx8 >> 7;
    int l = m & (LL - 1);

    float acc[8];
    float4 cb0 = *(const float4*)(cb + c0);
    float4 cb1 = *(const float4*)(cb + c0 + 4);
    acc[0] = cb0.x; acc[1] = cb0.y; acc[2] = cb0.z; acc[3] = cb0.w;
    acc[4] = cb1.x; acc[5] = cb1.y; acc[6] = cb1.z; acc[7] = cb1.w;
#pragma unroll
    for (int k = 0; k < DC; ++k) {
        int ll = l + k - (DC - 1);
        if (ll < 0) continue;
        const u16* row = xzb + ((size_t)(m + k - (DC - 1))) * (2 * DI) + c0;
        ushort4 r0 = *(const ushort4*)row;
        ushort4 r1 = *(const ushort4*)(row + 4);
#pragma unroll
        for (int j = 0; j < 4; ++j) {
            acc[j]     += cw[(c0 + j) * DC + k]     * bf2f(((const u16*)&r0)[j]);
            acc[j + 4] += cw[(c0 + j + 4) * DC + k] * bf2f(((const u16*)&r1)[j]);
        }
    }
    ushort4 o0, o1;
#pragma unroll
    for (int j = 0; j < 4; ++j) {
        float v0 = acc[j]     / (1.f + __expf(-acc[j]));
        float v1 = acc[j + 4] / (1.f + __expf(-acc[j + 4]));
        ((u16*)&o0)[j] = f2bf(v0);
        ((u16*)&o1)[j] = f2bf(v1);
    }
    u16* op = xcb + (size_t)idx8 * 8;
    *(ushort4*)op = o0;
    *(ushort4*)(op + 4) = o1;
}

// ---------------------------------------------------------------------------
// Fused cooperative scan: phase1 (chunk aggregate) -> grid.sync ->
// phase2 (serial combine, first 32768 global threads) -> grid.sync ->
// phase3 (rerun from start state; gated bf16 y).
// grid (DI/256=4, BB=2, CCH=64) = 512 blocks x 256 thr = 2 blocks/CU.
// LDS xds and registers (wreg, a, dtbv) persist across grid syncs.
// ---------------------------------------------------------------------------
__global__ __launch_bounds__(256) void scan_coop(const u16* __restrict__ xcb,
                                                 const float* __restrict__ Pf,
                                                 const float* __restrict__ dtw,
                                                 const float* __restrict__ dtb,
                                                 const u16* __restrict__ xzb,
                                                 const float* __restrict__ A_log,
                                                 const float* __restrict__ Dpp,
                                                 float* S,
                                                 float* Q,
                                                 u16* __restrict__ y) {
    __shared__ float xds[CHLEN][64];
    const int t = threadIdx.x;
    const int d = blockIdx.x * 256 + t;
    const int b = blockIdx.y;
    const int c = blockIdx.z;
    const int l0 = c * CHLEN;
    const int m0 = b * LL + l0;

    // Pf K-split reduce into LDS (persists through both phases)
    for (int i = t; i < CHLEN * 64; i += 256) {
        int r = i >> 6, cc = i & 63;
        float s = 0.f;
#pragma unroll
        for (int kz = 0; kz < KSPLIT; ++kz)
            s += Pf[(size_t)kz * (M_ROWS * 64) + (m0 + r) * 64 + cc];
        xds[r][cc] = s;
    }
    __syncthreads();

    float4 wreg[8];
#pragma unroll
    for (int kk = 0; kk < 8; ++kk)
        wreg[kk] = *(const float4*)(dtw + (size_t)d * DR + kk * 4);
    const float dtbv = dtb[d];

    float a[DS];
#pragma unroll
    for (int q = 0; q < 4; ++q) {
        float4 al = *(const float4*)(A_log + d * DS + q * 4);
        a[q * 4 + 0] = -__expf(al.x);
        a[q * 4 + 1] = -__expf(al.y);
        a[q * 4 + 2] = -__expf(al.z);
        a[q * 4 + 3] = -__expf(al.w);
    }

    // ---- phase 1: chunk aggregate (h_in = 0) ----
    float Qr[DS];
#pragma unroll
    for (int n = 0; n < DS; ++n) Qr[n] = 0.f;
    float Ssum = 0.f;
    const u16* up = xcb + (size_t)m0 * DI + d;

    for (int l = 0; l < CHLEN; ++l) {
        float dacc = dtbv;
#pragma unroll
        for (int kk = 0; kk < 8; ++kk) {
            float4 xv = *(const float4*)&xds[l][kk * 4];
            dacc += wreg[kk].x * xv.x + wreg[kk].y * xv.y +
                    wreg[kk].z * xv.z + wreg[kk].w * xv.w;
        }
        float dtv = (dacc > 20.f) ? dacc : log1pf(__expf(dacc));
        float uv = bf2f(up[(size_t)l * DI]);
        float wv = dtv * uv;
        Ssum += dtv;
#pragma unroll
        for (int q = 0; q < 4; ++q) {
            float4 Bv = *(const float4*)&xds[l][32 + q * 4];
            float dA0 = __expf(dtv * a[q * 4 + 0]);
            float dA1 = __expf(dtv * a[q * 4 + 1]);
            float dA2 = __expf(dtv * a[q * 4 + 2]);
            float dA3 = __expf(dtv * a[q * 4 + 3]);
            Qr[q * 4 + 0] = dA0 * Qr[q * 4 + 0] + wv * Bv.x;
            Qr[q * 4 + 1] = dA1 * Qr[q * 4 + 1] + wv * Bv.y;
            Qr[q * 4 + 2] = dA2 * Qr[q * 4 + 2] + wv * Bv.z;
            Qr[q * 4 + 3] = dA3 * Qr[q * 4 + 3] + wv * Bv.w;
        }
    }
    S[((size_t)b * CCH + c) * DI + d] = Ssum;
    {
        float* Qp = Q + (((size_t)b * CCH + c) * DI + d) * DS;
#pragma unroll
        for (int q = 0; q < 4; ++q) {
            float4 o;
            o.x = Qr[q * 4 + 0]; o.y = Qr[q * 4 + 1];
            o.z = Qr[q * 4 + 2]; o.w = Qr[q * 4 + 3];
            *(float4*)(Qp + q * 4) = o;
        }
    }

    cg::this_grid().sync();

    // ---- phase 2: serial combine (first 32768 global threads) ----
    {
        const int fid = (blockIdx.z * gridDim.y + blockIdx.y) * gridDim.x + blockIdx.x;
        const int gtid = fid * 256 + t;
        if (gtid < BB * DI * DS) {
            const int b2 = gtid >> 14;
            const int dn = gtid & 16383;
            const int d2 = dn >> 4;
            const float a2 = -__expf(A_log[dn]);
            float h2 = 0.f;
            for (int c2 = 0; c2 < CCH; ++c2) {
                const size_t soff = ((size_t)b2 * CCH + c2) * DI + d2;
                const size_t qoff = ((size_t)b2 * CCH + c2) * (size_t)(DI * DS) + dn;
                float P = __expf(a2 * S[soff]);
                float qv = Q[qoff];
                Q[qoff] = h2;                        // chunk START state
                h2 = P * h2 + qv;
            }
        }
    }

    cg::this_grid().sync();

    // ---- phase 3: rerun from start state (xds, wreg, a still live) ----
    float h[DS];
    {
        const float* Qp = Q + (((size_t)b * CCH + c) * DI + d) * DS;
#pragma unroll
        for (int q = 0; q < 4; ++q) {
            float4 hv = *(const float4*)(Qp + q * 4);
            h[q * 4 + 0] = hv.x; h[q * 4 + 1] = hv.y;
            h[q * 4 + 2] = hv.z; h[q * 4 + 3] = hv.w;
        }
    }
    const float dp = Dpp[d];
    const u16* zp = xzb + (size_t)m0 * (2 * DI) + DI + d;
    u16* yp = y + (size_t)m0 * DI + d;

    for (int l = 0; l < CHLEN; ++l) {
        float dacc = dtbv;
#pragma unroll
        for (int kk = 0; kk < 8; ++kk) {
            float4 xv = *(const float4*)&xds[l][kk * 4];
            dacc += wreg[kk].x * xv.x + wreg[kk].y * xv.y +
                    wreg[kk].z * xv.z + wreg[kk].w * xv.w;
        }
        float dtv = (dacc > 20.f) ? dacc : log1pf(__expf(dacc));
        float uv = bf2f(up[(size_t)l * DI]);
        float wv = dtv * uv;
        float p = 0.f;
#pragma unroll
        for (int q = 0; q < 4; ++q) {
            float4 Bv = *(const float4*)&xds[l][32 + q * 4];
            float4 Cv = *(const float4*)&xds[l][48 + q * 4];
            float dA0 = __expf(dtv * a[q * 4 + 0]);
            float dA1 = __expf(dtv * a[q * 4 + 1]);
            float dA2 = __expf(dtv * a[q * 4 + 2]);
            float dA3 = __expf(dtv * a[q * 4 + 3]);
            h[q * 4 + 0] = dA0 * h[q * 4 + 0] + wv * Bv.x;
            h[q * 4 + 1] = dA1 * h[q * 4 + 1] + wv * Bv.y;
            h[q * 4 + 2] = dA2 * h[q * 4 + 2] + wv * Bv.z;
            h[q * 4 + 3] = dA3 * h[q * 4 + 3] + wv * Bv.w;
            p += h[q * 4 + 0] * Cv.x + h[q * 4 + 1] * Cv.y +
                 h[q * 4 + 2] * Cv.z + h[q * 4 + 3] * Cv.w;
        }
        float zv = bf2f(zp[(size_t)l * (2 * DI)]);
        float g = zv / (1.f + __expf(-zv));
        yp[(size_t)l * DI] = f2bf((p + uv * dp) * g);
    }
}

// ---------------------------------------------------------------------------
// x = LayerNorm(x + sum_kz opart) * g + b   (+ bf16 shadow)
// ---------------------------------------------------------------------------
__global__ __launch_bounds__(256) void add_ln(const float* __restrict__ opart,
                                              float* __restrict__ x,
                                              const float* __restrict__ g,
                                              const float* __restrict__ b,
                                              u16* __restrict__ xb) {
    const int PS = M_ROWS * DIM;
    int m = blockIdx.x;
    int t = threadIdx.x;
    const float* xr = x + (size_t)m * DIM;
    float v0 = xr[t];
    float v1 = xr[t + 256];
#pragma unroll
    for (int kz = 0; kz < OSPLIT; ++kz) {
        const float* op = opart + (size_t)kz * PS + (size_t)m * DIM;
        v0 += op[t];
        v1 += op[t + 256];
    }
    float s = v0 + v1;
    float ss = v0 * v0 + v1 * v1;
#pragma unroll
    for (int off = 32; off > 0; off >>= 1) {
        s += __shfl_down(s, off, 64);
        ss += __shfl_down(ss, off, 64);
    }
    __shared__ float sb[4], ssb[4];
    int w = t >> 6;
    if ((t & 63) == 0) { sb[w] = s; ssb[w] = ss; }
    __syncthreads();
    float stot = sb[0] + sb[1] + sb[2] + sb[3];
    float sstot = ssb[0] + ssb[1] + ssb[2] + ssb[3];
    float mean = stot * (1.f / DIM);
    float var = sstot * (1.f / DIM) - mean * mean;
    float rs = rsqrtf(var + 1e-5f);
    float* xw = x + (size_t)m * DIM;
    float o0 = (v0 - mean) * rs * g[t] + b[t];
    float o1 = (v1 - mean) * rs * g[t + 256] + b[t + 256];
    xw[t] = o0;
    xw[t + 256] = o1;
    xb[(size_t)m * DIM + t] = f2bf(o0);
    xb[(size_t)m * DIM + t + 256] = f2bf(o1);
}

// ---------------------------------------------------------------------------
extern "C" void kernel_launch(void* const* d_in, const int* in_sizes, int n_in,
                              void* d_out, int out_size, void* d_ws, size_t ws_size,
                              hipStream_t stream) {
    const int*   tokens = (const int*)d_in[0];
    const float* pos    = (const float*)d_in[1];
    const float* emb    = (const float*)d_in[2];
    const float* lm_w   = (const float*)d_in[3];
    const float* lm_b   = (const float*)d_in[4];
    const float* in_w   = (const float*)d_in[5];
    const float* cw     = (const float*)d_in[6];
    const float* cb     = (const float*)d_in[7];
    const float* xpw    = (const float*)d_in[8];
    const float* dtw    = (const float*)d_in[9];
    const float* dtb    = (const float*)d_in[10];
    const float* A_log  = (const float*)d_in[11];
    const float* Dpp    = (const float*)d_in[12];
    const float* ow     = (const float*)d_in[13];
    const float* lng    = (const float*)d_in[14];
    const float* lnb    = (const float*)d_in[15];
    float* out = (float*)d_out;

    float* ws = (float*)d_ws;
    float* x    = ws;                    // 1048576
    float* S    = x + 1048576;           // 131072
    float* Qb   = S + 131072;            // 2097152
    float* Pf   = Qb + 2097152;          // KSPLIT*2048*64 = 1048576
    float* Pf2  = Pf + 1048576;          // OSPLIT*2048*512 = 2097152
    u16* xzb    = (u16*)(Pf2 + 2097152); // 4194304 u16
    u16* xb     = xzb + 4194304;         // 1048576
    u16* yb     = xb + 1048576;          // 2097152
    u16* xcb    = yb + 2097152;          // 2097152
    u16* lm_wb  = xcb + 2097152;         // 16384000
    u16* in_wb  = lm_wb + 16384000;      // 6291456
    u16* owb    = in_wb + 6291456;       // 3145728
    u16* xpwb   = owb + 3145728;         // 393216

    cast_all<<<12800, 256, 0, stream>>>(lm_w, in_w, ow, xpw,
                                        lm_wb, in_wb, owb, xpwb);

    embed_kernel<<<M_ROWS * DIM / 256, 256, 0, stream>>>(tokens, pos, emb, x, xb);

    for (int i = 0; i < NL; ++i) {
        // in_proj: (2048x2048x512), 128x64 tiles, bf16 out -> 512 blocks
        gemm_n64<<<dim3(1, M_ROWS / 128, 2048 / 64), 256, 0, stream>>>(
            xb, in_wb + (size_t)i * 2048 * 512, nullptr, xzb, nullptr,
            512, 512, 2048, 512, 0);
        conv_silu<<<M_ROWS * DI / 8 / 256, 256, 0, stream>>>(
            xzb, cw + (size_t)i * DI * DC, cb + (size_t)i * DI, xcb);
        // x_proj: (2048x64x1024), K-split 8 -> Pf
        gemm_n64<<<dim3(KSPLIT, M_ROWS / 128, 1), 256, 0, stream>>>(
            xcb, xpwb + (size_t)i * 64 * 1024, Pf, nullptr, nullptr,
            1024, 1024, 64, 1024 / KSPLIT, M_ROWS * 64);
        // fused cooperative scan (1 launch replaces pass1/2/3)
        {
            const u16* xcb_a = xcb;
            const float* Pf_a = Pf;
            const float* dtw_a = dtw + (size_t)i * DI * DR;
            const float* dtb_a = dtb + (size_t)i * DI;
            const u16* xzb_a = xzb;
            const float* Alog_a = A_log + (size_t)i * DI * DS;
            const float* Dpp_a = Dpp + (size_t)i * DI;
            float* S_a = S;
            float* Q_a = Qb;
            u16* y_a = yb;
            void* kargs[] = {(void*)&xcb_a, (void*)&Pf_a, (void*)&dtw_a,
                             (void*)&dtb_a, (void*)&xzb_a, (void*)&Alog_a,
                             (void*)&Dpp_a, (void*)&S_a, (void*)&Q_a,
                             (void*)&y_a};
            hipLaunchCooperativeKernel((const void*)scan_coop,
                                       dim3(DI / 256, BB, CCH), dim3(256),
                                       kargs, 0, stream);
        }
        // out_proj: (2048x512x1024), K-split 2 -> Pf2 -> 256 blocks
        gemm_n64<<<dim3(OSPLIT, M_ROWS / 128, 512 / 64), 256, 0, stream>>>(
            yb, owb + (size_t)i * 512 * 1024, Pf2, nullptr, nullptr,
            1024, 1024, 512, 1024 / OSPLIT, M_ROWS * 512);
        add_ln<<<M_ROWS, 256, 0, stream>>>(
            Pf2, x, lng + (size_t)i * DIM, lnb + (size_t)i * DIM, xb);
    }

    // LM head: (2048x32000x512), 256x256 tiles -> 1000 blocks, 512 threads
    gemm_256<<<(M_ROWS / 256) * (VOCAB / 256), 512, 0, stream>>>(
        xb, lm_wb, out, lm_b, 512, VOCAB);
}

// Round 18
// 793.057 us; speedup vs baseline: 2.1077x; 2.1077x over previous
//
#include <hip/hip_runtime.h>
#include <hip/hip_bf16.h>
#include <math.h>

#define BB 2
#define LL 1024
#define DIM 512
#define NL 6
#define DI 1024
#define DS 16
#define DC 4
#define DR 32
#define VOCAB 32000
#define M_ROWS (BB * LL)   // 2048
#define CCH 64             // scan chunks
#define CHLEN (LL / CCH)   // 16
#define KSPLIT 8           // x_proj K-split
#define OSPLIT 2           // out_proj K-split

typedef unsigned short u16;
typedef __attribute__((ext_vector_type(8))) short bf16x8;
typedef __attribute__((ext_vector_type(4))) float f32x4;

__device__ __forceinline__ u16 f2bf(float f) {
    unsigned u = __float_as_uint(f);
    u += 0x7FFF + ((u >> 16) & 1);       // round-to-nearest-even
    return (u16)(u >> 16);
}
__device__ __forceinline__ float bf2f(u16 h) {
    return __uint_as_float(((unsigned)h) << 16);
}
// LDS chunk swizzle: row r, 16B-chunk c -> c ^ ((r>>1)&3)  (involution)
#define SWZ(r, c) ((c) ^ (((r) >> 1) & 3))

// ---------------------------------------------------------------------------
// fused fp32 -> bf16 weight cast (lm_w, in_w, ow, xpw)
// ---------------------------------------------------------------------------
__global__ __launch_bounds__(256) void cast_all(const float* __restrict__ lm,
                                                const float* __restrict__ inw,
                                                const float* __restrict__ ow,
                                                const float* __restrict__ xp,
                                                u16* __restrict__ lmb,
                                                u16* __restrict__ inb,
                                                u16* __restrict__ owb_,
                                                u16* __restrict__ xpb) {
    int idx = blockIdx.x * 256 + threadIdx.x;
    const float* src; u16* dst; int off;
    if (idx < 2048000)      { src = lm;  dst = lmb;  off = idx; }
    else if (idx < 2834432) { src = inw; dst = inb;  off = idx - 2048000; }
    else if (idx < 3227648) { src = ow;  dst = owb_; off = idx - 2834432; }
    else                    { src = xp;  dst = xpb;  off = idx - 3227648; }
    float4 v0 = ((const float4*)src)[off * 2];
    float4 v1 = ((const float4*)src)[off * 2 + 1];
    union { u16 h[8]; int4 v; } r;
    r.h[0] = f2bf(v0.x); r.h[1] = f2bf(v0.y); r.h[2] = f2bf(v0.z); r.h[3] = f2bf(v0.w);
    r.h[4] = f2bf(v1.x); r.h[5] = f2bf(v1.y); r.h[6] = f2bf(v1.z); r.h[7] = f2bf(v1.w);
    ((int4*)dst)[off] = r.v;
}

// ---------------------------------------------------------------------------
// embed + pos  (f32 x + bf16 shadow xb)
// ---------------------------------------------------------------------------
__global__ __launch_bounds__(256) void embed_kernel(const int* __restrict__ tok,
                                                    const float* __restrict__ pos,
                                                    const float* __restrict__ emb,
                                                    float* __restrict__ x,
                                                    u16* __restrict__ xb) {
    int idx = blockIdx.x * 256 + threadIdx.x;
    int d = idx & (DIM - 1);
    int l = (idx >> 9) & (LL - 1);
    int b = idx >> 19;
    int t = tok[b * LL + l];
    float v = emb[(size_t)t * DIM + d] + pos[l * DIM + d];
    x[idx] = v;
    xb[idx] = f2bf(v);
}

// ---------------------------------------------------------------------------
// 256x256 bf16 MFMA GEMM (LM head): 512 thr / 8 waves (2M x 4N),
// per-wave 128x64 (acc[8][4]).  BK=32, 3-buffer dist-2 counted vmcnt(8).
// LDS 96 KB staging (reused as 64x260 f32 C-stage); setprio on MFMA.
// ---------------------------------------------------------------------------
__global__ __launch_bounds__(512) void gemm_256(const u16* __restrict__ A,
                                                const u16* __restrict__ W,
                                                float* __restrict__ C,
                                                const float* __restrict__ bias,
                                                int K, int N) {
    __shared__ __align__(16) char smem_raw[98304];   // 3x16K A | 3x16K B ; C-stage
    u16* As = (u16*)smem_raw;                        // 3 * 8192 u16
    u16* Ws = (u16*)(smem_raw + 49152);              // 3 * 8192 u16
    float* Cs = (float*)smem_raw;                    // 64 x 260 f32

    const int t = threadIdx.x;                       // 0..511
    const int l = t & 63;
    const int w = t >> 6;                            // wave 0..7
    const int wr = w >> 2;                           // 0..1  (M dir)
    const int wc = w & 3;                            // 0..3  (N dir)

    const int nwg = gridDim.x;
    const int q8 = nwg >> 3, r8 = nwg & 7;
    const int xcd = blockIdx.x & 7, rank = blockIdx.x >> 3;
    const int wgid = (xcd < r8 ? xcd * (q8 + 1) : r8 * (q8 + 1) + (xcd - r8) * q8) + rank;
    const int bm = (wgid & 7) * 256;
    const int bn = (wgid >> 3) * 256;

    f32x4 acc[8][4] = {};
    const int nt = K >> 5;                           // 16 for K=512

    auto STAGE = [&](int bufi, int k0) {
#pragma unroll
        for (int p = 0; p < 2; ++p) {
            const int g = p * 512 + t;               // chunk id 0..1023
            const int row = g >> 2, slot = g & 3;
            __builtin_amdgcn_global_load_lds(
                (const __attribute__((address_space(1))) unsigned int*)
                    (A + (size_t)(bm + row) * K + k0 + SWZ(row, slot) * 8),
                (__attribute__((address_space(3))) unsigned int*)
                    (As + bufi * 8192 + (p * 512 + w * 64) * 8),
                16, 0, 0);
        }
#pragma unroll
        for (int p = 0; p < 2; ++p) {
            const int g = p * 512 + t;
            const int row = g >> 2, slot = g & 3;
            __builtin_amdgcn_global_load_lds(
                (const __attribute__((address_space(1))) unsigned int*)
                    (W + (size_t)(bn + row) * K + k0 + SWZ(row, slot) * 8),
                (__attribute__((address_space(3))) unsigned int*)
                    (Ws + bufi * 8192 + (p * 512 + w * 64) * 8),
                16, 0, 0);
        }
    };
    auto COMPUTE = [&](int bufi) {
        const u16* Ab = As + bufi * 8192;
        const u16* Wb = Ws + bufi * 8192;
        bf16x8 bfr[4];
#pragma unroll
        for (int ni = 0; ni < 4; ++ni) {
            const int wrow = wc * 64 + ni * 16 + (l & 15);
            bfr[ni] = *(const bf16x8*)(Wb + wrow * 32 + SWZ(wrow, l >> 4) * 8);
        }
        __builtin_amdgcn_s_setprio(1);
#pragma unroll
        for (int mi = 0; mi < 8; ++mi) {
            const int arow = wr * 128 + mi * 16 + (l & 15);
            bf16x8 a = *(const bf16x8*)(Ab + arow * 32 + SWZ(arow, l >> 4) * 8);
#pragma unroll
            for (int ni = 0; ni < 4; ++ni)
                acc[mi][ni] = __builtin_amdgcn_mfma_f32_16x16x32_bf16(bfr[ni], a, acc[mi][ni], 0, 0, 0);
        }
        __builtin_amdgcn_s_setprio(0);
    };

    STAGE(0, 0);
    STAGE(1, 32);
    int b0 = 0;
    for (int tt = 0; tt < nt - 2; ++tt) {
        int b2 = b0 + 2; if (b2 >= 3) b2 -= 3;
        STAGE(b2, (tt + 2) << 5);
        asm volatile("s_waitcnt vmcnt(8)\ns_barrier" ::: "memory");
        COMPUTE(b0);
        asm volatile("s_waitcnt lgkmcnt(0)\ns_barrier" ::: "memory");
        ++b0; if (b0 == 3) b0 = 0;
    }
    asm volatile("s_waitcnt vmcnt(4)\ns_barrier" ::: "memory");
    COMPUTE(b0);
    asm volatile("s_waitcnt lgkmcnt(0)\ns_barrier" ::: "memory");
    ++b0; if (b0 == 3) b0 = 0;
    asm volatile("s_waitcnt vmcnt(0)\ns_barrier" ::: "memory");
    COMPUTE(b0);
    asm volatile("s_waitcnt lgkmcnt(0)" ::: "memory");
    __syncthreads();

    // epilogue: 4 passes of 64 rows x 256 cols via LDS (1 KB/row stores)
#pragma unroll
    for (int pass = 0; pass < 4; ++pass) {
        if (wr == (pass >> 1)) {
            const int pm0 = (pass & 1) * 4;
#pragma unroll
            for (int mi2 = 0; mi2 < 4; ++mi2) {
                const int r = mi2 * 16 + (l & 15);
#pragma unroll
                for (int ni = 0; ni < 4; ++ni) {
                    const int c = wc * 64 + ni * 16 + ((l >> 4) << 2);
                    float4 v;
                    v.x = acc[pm0 + mi2][ni][0]; v.y = acc[pm0 + mi2][ni][1];
                    v.z = acc[pm0 + mi2][ni][2]; v.w = acc[pm0 + mi2][ni][3];
                    *(float4*)(Cs + r * 260 + c) = v;
                }
            }
        }
        __syncthreads();
#pragma unroll
        for (int it = 0; it < 8; ++it) {
            const int idx = it * 512 + t;            // 0..4095
            const int r = idx >> 6;
            const int c4 = (idx & 63) * 4;
            float4 v = *(float4*)(Cs + r * 260 + c4);
            if (bias != nullptr) {
                float4 b4 = *(const float4*)(bias + bn + c4);
                v.x += b4.x; v.y += b4.y; v.z += b4.z; v.w += b4.w;
            }
            *(float4*)(C + (size_t)(bm + pass * 64 + r) * N + bn + c4) = v;
        }
        __syncthreads();
    }
}

// ---------------------------------------------------------------------------
// bf16 MFMA GEMM, 128M x 64N tile, BK=32, K-split, 3-buffer dist-2.
// (layer GEMMs)  f32 out: LDS-staged epilogue + bias; bf16 out: direct.
// ---------------------------------------------------------------------------
__global__ __launch_bounds__(256) void gemm_n64(const u16* __restrict__ A,
                                                const u16* __restrict__ W,
                                                float* __restrict__ out,
                                                u16* __restrict__ outb,
                                                const float* __restrict__ bias,
                                                int lda, int ldw, int ldc,
                                                int KS, int pstride) {
    __shared__ __align__(16) char smem_raw[36864];   // As 24K | Ws 12K ; C-stage reuse
    u16* As = (u16*)smem_raw;
    u16* Ws = (u16*)(smem_raw + 24576);
    float* Cs = (float*)smem_raw;

    const int t = threadIdx.x;
    const int l = t & 63;
    const int w = t >> 6;
    const int gx = gridDim.x, gy = gridDim.y;
    const int nwg = gx * gy * gridDim.z;
    const int fid = (blockIdx.z * gy + blockIdx.y) * gx + blockIdx.x;
    const int q8 = nwg >> 3, r8 = nwg & 7;
    const int xcd = fid & 7, rank = fid >> 3;
    const int wgid = (xcd < r8 ? xcd * (q8 + 1) : r8 * (q8 + 1) + (xcd - r8) * q8) + rank;
    const int kz = wgid % gx;
    const int bm = ((wgid / gx) % gy) * 128;
    const int bnn = (wgid / (gx * gy)) * 64;
    const int wm = w * 32;

    f32x4 acc[2][4] = {};
    const int nt = KS >> 5;
    const int kbeg = kz * KS;

    auto STAGE = [&](int bufi, int k0) {
#pragma unroll
        for (int p = 0; p < 2; ++p) {
            const int i = p * 256 + w * 64 + l;
            const int row = i >> 2;
            const int kq = SWZ(row, i & 3);
            __builtin_amdgcn_global_load_lds(
                (const __attribute__((address_space(1))) unsigned int*)
                    (A + (size_t)(bm + row) * lda + k0 + kq * 8),
                (__attribute__((address_space(3))) unsigned int*)
                    (As + bufi * 4096 + (p * 256 + w * 64) * 8),
                16, 0, 0);
        }
        {
            const int i = w * 64 + l;
            const int row = i >> 2;
            const int kq = SWZ(row, i & 3);
            __builtin_amdgcn_global_load_lds(
                (const __attribute__((address_space(1))) unsigned int*)
                    (W + (size_t)(bnn + row) * ldw + k0 + kq * 8),
                (__attribute__((address_space(3))) unsigned int*)
                    (Ws + bufi * 2048 + (w * 64) * 8),
                16, 0, 0);
        }
    };
    auto COMPUTE = [&](int bufi) {
        const u16* Ab = As + bufi * 4096;
        const u16* Wb = Ws + bufi * 2048;
        bf16x8 bfr[4];
#pragma unroll
        for (int ni = 0; ni < 4; ++ni) {
            const int wr2 = ni * 16 + (l & 15);
            bfr[ni] = *(const bf16x8*)(Wb + wr2 * 32 + SWZ(wr2, l >> 4) * 8);
        }
        __builtin_amdgcn_s_setprio(1);
#pragma unroll
        for (int mi = 0; mi < 2; ++mi) {
            const int ar = wm + mi * 16 + (l & 15);
            bf16x8 a = *(const bf16x8*)(Ab + ar * 32 + SWZ(ar, l >> 4) * 8);
#pragma unroll
            for (int ni = 0; ni < 4; ++ni)
                acc[mi][ni] = __builtin_amdgcn_mfma_f32_16x16x32_bf16(bfr[ni], a, acc[mi][ni], 0, 0, 0);
        }
        __builtin_amdgcn_s_setprio(0);
    };

    STAGE(0, kbeg);
    if (nt == 1) {
        asm volatile("s_waitcnt vmcnt(0)\ns_barrier" ::: "memory");
        COMPUTE(0);
        asm volatile("s_waitcnt lgkmcnt(0)" ::: "memory");
    } else {
        STAGE(1, kbeg + 32);
        int b0 = 0;
        for (int tt = 0; tt < nt - 2; ++tt) {
            int b2 = b0 + 2; if (b2 >= 3) b2 -= 3;
            STAGE(b2, kbeg + ((tt + 2) << 5));
            asm volatile("s_waitcnt vmcnt(6)\ns_barrier" ::: "memory");
            COMPUTE(b0);
            asm volatile("s_waitcnt lgkmcnt(0)\ns_barrier" ::: "memory");
            ++b0; if (b0 == 3) b0 = 0;
        }
        asm volatile("s_waitcnt vmcnt(3)\ns_barrier" ::: "memory");
        COMPUTE(b0);
        asm volatile("s_waitcnt lgkmcnt(0)\ns_barrier" ::: "memory");
        ++b0; if (b0 == 3) b0 = 0;
        asm volatile("s_waitcnt vmcnt(0)\ns_barrier" ::: "memory");
        COMPUTE(b0);
        asm volatile("s_waitcnt lgkmcnt(0)" ::: "memory");
    }

    if (outb != nullptr) {
        u16* opb = outb + (size_t)kz * pstride;
#pragma unroll
        for (int mi = 0; mi < 2; ++mi) {
            const int row = bm + wm + mi * 16 + (l & 15);
#pragma unroll
            for (int ni = 0; ni < 4; ++ni) {
                const int col = bnn + ni * 16 + ((l >> 4) << 2);
                ushort4 v;
                v.x = f2bf(acc[mi][ni][0]); v.y = f2bf(acc[mi][ni][1]);
                v.z = f2bf(acc[mi][ni][2]); v.w = f2bf(acc[mi][ni][3]);
                *(ushort4*)(opb + (size_t)row * ldc + col) = v;
            }
        }
    } else {
        float* op = out + (size_t)kz * pstride;
        __syncthreads();
#pragma unroll
        for (int pass = 0; pass < 2; ++pass) {
            if ((w >> 1) == pass) {
                const int rbase = (w & 1) * 32;
#pragma unroll
                for (int mi = 0; mi < 2; ++mi) {
                    const int r = rbase + mi * 16 + (l & 15);
#pragma unroll
                    for (int ni = 0; ni < 4; ++ni) {
                        const int c = ni * 16 + ((l >> 4) << 2);
                        float4 v;
                        v.x = acc[mi][ni][0]; v.y = acc[mi][ni][1];
                        v.z = acc[mi][ni][2]; v.w = acc[mi][ni][3];
                        *(float4*)(Cs + r * 65 + c) = v;
                    }
                }
            }
            __syncthreads();
#pragma unroll
            for (int it = 0; it < 4; ++it) {
                const int idx = it * 256 + t;
                const int r = idx >> 4;
                const int c4 = (idx & 15) * 4;
                float4 v = *(float4*)(Cs + r * 65 + c4);
                if (bias != nullptr) {
                    float4 b4 = *(const float4*)(bias + bnn + c4);
                    v.x += b4.x; v.y += b4.y; v.z += b4.z; v.w += b4.w;
                }
                *(float4*)(op + (size_t)(bm + pass * 64 + r) * ldc + bnn + c4) = v;
            }
            __syncthreads();
        }
    }
}

// ---------------------------------------------------------------------------
// causal depthwise conv (DC=4) + SiLU, 8 channels/thread (short8 I/O)
// ---------------------------------------------------------------------------
__global__ __launch_bounds__(256) void conv_silu(const u16* __restrict__ xzb,
                                                 const float* __restrict__ cw,
                                                 const float* __restrict__ cb,
                                                 u16* __restrict__ xcb) {
    int idx8 = blockIdx.x * 256 + threadIdx.x;
    int c0 = (idx8 & 127) * 8;
    int m = idx8 >> 7;
    int l = m & (LL - 1);

    float acc[8];
    float4 cb0 = *(const float4*)(cb + c0);
    float4 cb1 = *(const float4*)(cb + c0 + 4);
    acc[0] = cb0.x; acc[1] = cb0.y; acc[2] = cb0.z; acc[3] = cb0.w;
    acc[4] = cb1.x; acc[5] = cb1.y; acc[6] = cb1.z; acc[7] = cb1.w;
#pragma unroll
    for (int k = 0; k < DC; ++k) {
        int ll = l + k - (DC - 1);
        if (ll < 0) continue;
        const u16* row = xzb + ((size_t)(m + k - (DC - 1))) * (2 * DI) + c0;
        ushort4 r0 = *(const ushort4*)row;
        ushort4 r1 = *(const ushort4*)(row + 4);
#pragma unroll
        for (int j = 0; j < 4; ++j) {
            acc[j]     += cw[(c0 + j) * DC + k]     * bf2f(((const u16*)&r0)[j]);
            acc[j + 4] += cw[(c0 + j + 4) * DC + k] * bf2f(((const u16*)&r1)[j]);
        }
    }
    ushort4 o0, o1;
#pragma unroll
    for (int j = 0; j < 4; ++j) {
        float v0 = acc[j]     / (1.f + __expf(-acc[j]));
        float v1 = acc[j + 4] / (1.f + __expf(-acc[j + 4]));
        ((u16*)&o0)[j] = f2bf(v0);
        ((u16*)&o1)[j] = f2bf(v1);
    }
    u16* op = xcb + (size_t)idx8 * 8;
    *(ushort4*)op = o0;
    *(ushort4*)(op + 4) = o1;
}

// ---------------------------------------------------------------------------
// scan pass 1 (fused Pf-reduce + dt recompute).  grid (DI/256, BB, CCH).
// ---------------------------------------------------------------------------
__global__ __launch_bounds__(256) void scan_pass1(const u16* __restrict__ xcb,
                                                  const float* __restrict__ Pf,
                                                  const float* __restrict__ dtw,
                                                  const float* __restrict__ dtb,
                                                  const float* __restrict__ A_log,
                                                  float* __restrict__ S,
                                                  float* __restrict__ Q) {
    __shared__ float xds[CHLEN][64];
    const int t = threadIdx.x;
    const int d = blockIdx.x * 256 + t;
    const int b = blockIdx.y;
    const int c = blockIdx.z;
    const int l0 = c * CHLEN;
    const int m0 = b * LL + l0;

    for (int i = t; i < CHLEN * 64; i += 256) {
        int r = i >> 6, cc = i & 63;
        float s = 0.f;
#pragma unroll
        for (int kz = 0; kz < KSPLIT; ++kz)
            s += Pf[(size_t)kz * (M_ROWS * 64) + (m0 + r) * 64 + cc];
        xds[r][cc] = s;
    }
    __syncthreads();

    float4 wreg[8];
#pragma unroll
    for (int kk = 0; kk < 8; ++kk)
        wreg[kk] = *(const float4*)(dtw + (size_t)d * DR + kk * 4);
    const float dtbv = dtb[d];

    float a[DS];
#pragma unroll
    for (int q = 0; q < 4; ++q) {
        float4 al = *(const float4*)(A_log + d * DS + q * 4);
        a[q * 4 + 0] = -__expf(al.x);
        a[q * 4 + 1] = -__expf(al.y);
        a[q * 4 + 2] = -__expf(al.z);
        a[q * 4 + 3] = -__expf(al.w);
    }
    float Qr[DS];
#pragma unroll
    for (int n = 0; n < DS; ++n) Qr[n] = 0.f;
    float Ssum = 0.f;

    const u16* up = xcb + (size_t)m0 * DI + d;

    for (int l = 0; l < CHLEN; ++l) {
        float dacc = dtbv;
#pragma unroll
        for (int kk = 0; kk < 8; ++kk) {
            float4 xv = *(const float4*)&xds[l][kk * 4];
            dacc += wreg[kk].x * xv.x + wreg[kk].y * xv.y +
                    wreg[kk].z * xv.z + wreg[kk].w * xv.w;
        }
        float dtv = (dacc > 20.f) ? dacc : log1pf(__expf(dacc));
        float uv = bf2f(up[(size_t)l * DI]);
        float wv = dtv * uv;
        Ssum += dtv;
#pragma unroll
        for (int q = 0; q < 4; ++q) {
            float4 Bv = *(const float4*)&xds[l][32 + q * 4];
            float dA0 = __expf(dtv * a[q * 4 + 0]);
            float dA1 = __expf(dtv * a[q * 4 + 1]);
            float dA2 = __expf(dtv * a[q * 4 + 2]);
            float dA3 = __expf(dtv * a[q * 4 + 3]);
            Qr[q * 4 + 0] = dA0 * Qr[q * 4 + 0] + wv * Bv.x;
            Qr[q * 4 + 1] = dA1 * Qr[q * 4 + 1] + wv * Bv.y;
            Qr[q * 4 + 2] = dA2 * Qr[q * 4 + 2] + wv * Bv.z;
            Qr[q * 4 + 3] = dA3 * Qr[q * 4 + 3] + wv * Bv.w;
        }
    }
    S[((size_t)b * CCH + c) * DI + d] = Ssum;
    float* Qp = Q + (((size_t)b * CCH + c) * DI + d) * DS;
#pragma unroll
    for (int q = 0; q < 4; ++q) {
        float4 o;
        o.x = Qr[q * 4 + 0]; o.y = Qr[q * 4 + 1];
        o.z = Qr[q * 4 + 2]; o.w = Qr[q * 4 + 3];
        *(float4*)(Qp + q * 4) = o;
    }
}

// ---------------------------------------------------------------------------
// Pass 2: sequential combine over chunks (64-thr blocks)
// ---------------------------------------------------------------------------
__global__ __launch_bounds__(64) void scan_pass2(const float* __restrict__ A_log,
                                                 const float* __restrict__ S,
                                                 float* __restrict__ Q) {
    const int idx = blockIdx.x * 64 + threadIdx.x;
    const int b = idx >> 14;
    const int dn = idx & 16383;
    const int d = dn >> 4;
    const float a = -__expf(A_log[dn]);
    float h = 0.f;
    for (int c = 0; c < CCH; ++c) {
        const size_t soff = ((size_t)b * CCH + c) * DI + d;
        const size_t qoff = ((size_t)b * CCH + c) * (size_t)(DI * DS) + dn;
        float P = __expf(a * S[soff]);
        float qv = Q[qoff];
        Q[qoff] = h;
        h = P * h + qv;
    }
}

// ---------------------------------------------------------------------------
// Pass 3: fused Pf-reduce + dt recompute; gated bf16 output
// ---------------------------------------------------------------------------
__global__ __launch_bounds__(256) void scan_pass3(const u16* __restrict__ xcb,
                                                  const float* __restrict__ Pf,
                                                  const float* __restrict__ dtw,
                                                  const float* __restrict__ dtb,
                                                  const u16* __restrict__ xzb,
                                                  const float* __restrict__ A_log,
                                                  const float* __restrict__ Dpp,
                                                  const float* __restrict__ Q,
                                                  u16* __restrict__ y) {
    __shared__ float xds[CHLEN][64];
    const int t = threadIdx.x;
    const int d = blockIdx.x * 256 + t;
    const int b = blockIdx.y;
    const int c = blockIdx.z;
    const int l0 = c * CHLEN;
    const int m0 = b * LL + l0;

    for (int i = t; i < CHLEN * 64; i += 256) {
        int r = i >> 6, cc = i & 63;
        float s = 0.f;
#pragma unroll
        for (int kz = 0; kz < KSPLIT; ++kz)
            s += Pf[(size_t)kz * (M_ROWS * 64) + (m0 + r) * 64 + cc];
        xds[r][cc] = s;
    }
    __syncthreads();

    float4 wreg[8];
#pragma unroll
    for (int kk = 0; kk < 8; ++kk)
        wreg[kk] = *(const float4*)(dtw + (size_t)d * DR + kk * 4);
    const float dtbv = dtb[d];

    float a[DS];
#pragma unroll
    for (int q = 0; q < 4; ++q) {
        float4 al = *(const float4*)(A_log + d * DS + q * 4);
        a[q * 4 + 0] = -__expf(al.x);
        a[q * 4 + 1] = -__expf(al.y);
        a[q * 4 + 2] = -__expf(al.z);
        a[q * 4 + 3] = -__expf(al.w);
    }
    float h[DS];
    const float* Qp = Q + (((size_t)b * CCH + c) * DI + d) * DS;
#pragma unroll
    for (int q = 0; q < 4; ++q) {
        float4 hv = *(const float4*)(Qp + q * 4);
        h[q * 4 + 0] = hv.x; h[q * 4 + 1] = hv.y;
        h[q * 4 + 2] = hv.z; h[q * 4 + 3] = hv.w;
    }
    const float dp = Dpp[d];

    const u16* up = xcb + (size_t)m0 * DI + d;
    const u16* zp = xzb + (size_t)m0 * (2 * DI) + DI + d;
    u16* yp = y + (size_t)m0 * DI + d;

    for (int l = 0; l < CHLEN; ++l) {
        float dacc = dtbv;
#pragma unroll
        for (int kk = 0; kk < 8; ++kk) {
            float4 xv = *(const float4*)&xds[l][kk * 4];
            dacc += wreg[kk].x * xv.x + wreg[kk].y * xv.y +
                    wreg[kk].z * xv.z + wreg[kk].w * xv.w;
        }
        float dtv = (dacc > 20.f) ? dacc : log1pf(__expf(dacc));
        float uv = bf2f(up[(size_t)l * DI]);
        float wv = dtv * uv;
        float p = 0.f;
#pragma unroll
        for (int q = 0; q < 4; ++q) {
            float4 Bv = *(const float4*)&xds[l][32 + q * 4];
            float4 Cv = *(const float4*)&xds[l][48 + q * 4];
            float dA0 = __expf(dtv * a[q * 4 + 0]);
            float dA1 = __expf(dtv * a[q * 4 + 1]);
            float dA2 = __expf(dtv * a[q * 4 + 2]);
            float dA3 = __expf(dtv * a[q * 4 + 3]);
            h[q * 4 + 0] = dA0 * h[q * 4 + 0] + wv * Bv.x;
            h[q * 4 + 1] = dA1 * h[q * 4 + 1] + wv * Bv.y;
            h[q * 4 + 2] = dA2 * h[q * 4 + 2] + wv * Bv.z;
            h[q * 4 + 3] = dA3 * h[q * 4 + 3] + wv * Bv.w;
            p += h[q * 4 + 0] * Cv.x + h[q * 4 + 1] * Cv.y +
                 h[q * 4 + 2] * Cv.z + h[q * 4 + 3] * Cv.w;
        }
        float zv = bf2f(zp[(size_t)l * (2 * DI)]);
        float g = zv / (1.f + __expf(-zv));
        yp[(size_t)l * DI] = f2bf((p + uv * dp) * g);
    }
}

// ---------------------------------------------------------------------------
// x = LayerNorm(x + sum_kz opart) * g + b   (+ bf16 shadow)
// ---------------------------------------------------------------------------
__global__ __launch_bounds__(256) void add_ln(const float* __restrict__ opart,
                                              float* __restrict__ x,
                                              const float* __restrict__ g,
                                              const float* __restrict__ b,
                                              u16* __restrict__ xb) {
    const int PS = M_ROWS * DIM;
    int m = blockIdx.x;
    int t = threadIdx.x;
    const float* xr = x + (size_t)m * DIM;
    float v0 = xr[t];
    float v1 = xr[t + 256];
#pragma unroll
    for (int kz = 0; kz < OSPLIT; ++kz) {
        const float* op = opart + (size_t)kz * PS + (size_t)m * DIM;
        v0 += op[t];
        v1 += op[t + 256];
    }
    float s = v0 + v1;
    float ss = v0 * v0 + v1 * v1;
#pragma unroll
    for (int off = 32; off > 0; off >>= 1) {
        s += __shfl_down(s, off, 64);
        ss += __shfl_down(ss, off, 64);
    }
    __shared__ float sb[4], ssb[4];
    int w = t >> 6;
    if ((t & 63) == 0) { sb[w] = s; ssb[w] = ss; }
    __syncthreads();
    float stot = sb[0] + sb[1] + sb[2] + sb[3];
    float sstot = ssb[0] + ssb[1] + ssb[2] + ssb[3];
    float mean = stot * (1.f / DIM);
    float var = sstot * (1.f / DIM) - mean * mean;
    float rs = rsqrtf(var + 1e-5f);
    float* xw = x + (size_t)m * DIM;
    float o0 = (v0 - mean) * rs * g[t] + b[t];
    float o1 = (v1 - mean) * rs * g[t + 256] + b[t + 256];
    xw[t] = o0;
    xw[t + 256] = o1;
    xb[(size_t)m * DIM + t] = f2bf(o0);
    xb[(size_t)m * DIM + t + 256] = f2bf(o1);
}

// ---------------------------------------------------------------------------
extern "C" void kernel_launch(void* const* d_in, const int* in_sizes, int n_in,
                              void* d_out, int out_size, void* d_ws, size_t ws_size,
                              hipStream_t stream) {
    const int*   tokens = (const int*)d_in[0];
    const float* pos    = (const float*)d_in[1];
    const float* emb    = (const float*)d_in[2];
    const float* lm_w   = (const float*)d_in[3];
    const float* lm_b   = (const float*)d_in[4];
    const float* in_w   = (const float*)d_in[5];
    const float* cw     = (const float*)d_in[6];
    const float* cb     = (const float*)d_in[7];
    const float* xpw    = (const float*)d_in[8];
    const float* dtw    = (const float*)d_in[9];
    const float* dtb    = (const float*)d_in[10];
    const float* A_log  = (const float*)d_in[11];
    const float* Dpp    = (const float*)d_in[12];
    const float* ow     = (const float*)d_in[13];
    const float* lng    = (const float*)d_in[14];
    const float* lnb    = (const float*)d_in[15];
    float* out = (float*)d_out;

    float* ws = (float*)d_ws;
    float* x    = ws;                    // 1048576
    float* S    = x + 1048576;           // 131072
    float* Qb   = S + 131072;            // 2097152
    float* Pf   = Qb + 2097152;          // KSPLIT*2048*64 = 1048576
    float* Pf2  = Pf + 1048576;          // OSPLIT*2048*512 = 2097152
    u16* xzb    = (u16*)(Pf2 + 2097152); // 4194304 u16
    u16* xb     = xzb + 4194304;         // 1048576
    u16* yb     = xb + 1048576;          // 2097152
    u16* xcb    = yb + 2097152;          // 2097152
    u16* lm_wb  = xcb + 2097152;         // 16384000
    u16* in_wb  = lm_wb + 16384000;      // 6291456
    u16* owb    = in_wb + 6291456;       // 3145728
    u16* xpwb   = owb + 3145728;         // 393216

    cast_all<<<12800, 256, 0, stream>>>(lm_w, in_w, ow, xpw,
                                        lm_wb, in_wb, owb, xpwb);

    embed_kernel<<<M_ROWS * DIM / 256, 256, 0, stream>>>(tokens, pos, emb, x, xb);

    for (int i = 0; i < NL; ++i) {
        // in_proj: (2048x2048x512), 128x64 tiles, bf16 out -> 512 blocks
        gemm_n64<<<dim3(1, M_ROWS / 128, 2048 / 64), 256, 0, stream>>>(
            xb, in_wb + (size_t)i * 2048 * 512, nullptr, xzb, nullptr,
            512, 512, 2048, 512, 0);
        conv_silu<<<M_ROWS * DI / 8 / 256, 256, 0, stream>>>(
            xzb, cw + (size_t)i * DI * DC, cb + (size_t)i * DI, xcb);
        // x_proj: (2048x64x1024), K-split 8 -> Pf
        gemm_n64<<<dim3(KSPLIT, M_ROWS / 128, 1), 256, 0, stream>>>(
            xcb, xpwb + (size_t)i * 64 * 1024, Pf, nullptr, nullptr,
            1024, 1024, 64, 1024 / KSPLIT, M_ROWS * 64);
        scan_pass1<<<dim3(DI / 256, BB, CCH), 256, 0, stream>>>(
            xcb, Pf, dtw + (size_t)i * DI * DR, dtb + (size_t)i * DI,
            A_log + (size_t)i * DI * DS, S, Qb);
        scan_pass2<<<(BB * DI * DS) / 64, 64, 0, stream>>>(
            A_log + (size_t)i * DI * DS, S, Qb);
        scan_pass3<<<dim3(DI / 256, BB, CCH), 256, 0, stream>>>(
            xcb, Pf, dtw + (size_t)i * DI * DR, dtb + (size_t)i * DI, xzb,
            A_log + (size_t)i * DI * DS, Dpp + (size_t)i * DI, Qb, yb);
        // out_proj: (2048x512x1024), K-split 2 -> Pf2 -> 256 blocks
        gemm_n64<<<dim3(OSPLIT, M_ROWS / 128, 512 / 64), 256, 0, stream>>>(
            yb, owb + (size_t)i * 512 * 1024, Pf2, nullptr, nullptr,
            1024, 1024, 512, 1024 / OSPLIT, M_ROWS * 512);
        add_ln<<<M_ROWS, 256, 0, stream>>>(
            Pf2, x, lng + (size_t)i * DIM, lnb + (size_t)i * DIM, xb);
    }

    // LM head: (2048x32000x512), 256x256 tiles -> 1000 blocks, 512 threads
    gemm_256<<<(M_ROWS / 256) * (VOCAB / 256), 512, 0, stream>>>(
        xb, lm_wb, out, lm_b, 512, VOCAB);
}